// Round 12
// baseline (166.847 us; speedup 1.0000x reference)
//
#include <hip/hip_runtime.h>
#include <hip/hip_bf16.h>

// GCNConv encoder — R26:
//   prep:   zero bcursor + pre-swizzle W into MFMA B-fragment order (bf16, 8KB)
//   passA:  REVERTED to R24 (single-read multisplit, ACH=4096, 60KB LDS). R25's
//           double-read variant regressed (+2.8us): re-read not L2-warm across XCDs;
//           passA is barrier-bound, not wave-starved.
//   gemmF:  MFMA gemm + fused bucket-histogram + *rsqrt(deg+1), x-loads hoisted
//           [unchanged from R24]
//   B2:     SPLIT: each bucket -> 2 blocks by column parity (16 cols each, uint2
//           gathers, 4 cols/lane). Sort duplicated per pair (cheap, parallel CUs);
//           grid 782->1564 doubles independent latency chains chip-wide (B2 is
//           latency-bound: VALU 16-22%, TCC 1.6TB/s, grid-capped occupancy; per-wave
//           chains maxed by VGPR ceiling R22).
// LESSONS: per-edge ordered LDS ops in gather loop = serial chain (R15/16, 433us);
//          per-edge random global atomics = +60MB writes (R18, 103us);
//          divergent per-edge branches serialize the wave (R22->R23);
//          compiler splits >8-deep gather batches (R22, VGPR=36);
//          passA double-read not L2-warm (R25).
//
// Fragment layouts (learn_hip m89/m92-verified):
//   A: row = lane&15, k = 8*(lane>>4)+i (contiguous)   B: col = lane&15, same k-group
//   C/D: col = lane&15, row = 4*(lane>>4)+reg
//
// ws: dinv[n] f32 (fallback) | h[n*32] bf16 | bucketed[NB*CAP] u32 | bcursor[1024]+deg[n] | Wf[4096] bf16

#define LATD 32
#define INCH 128
#define BSH 7
#define BW 128
#define CAP 4096
#define ACH 4096

typedef short bf16x8 __attribute__((ext_vector_type(8)));   // 8 bf16 in 4 VGPRs
typedef float f32x4 __attribute__((ext_vector_type(4)));

__device__ __forceinline__ short f2bf(float f) {
    __hip_bfloat16 t = __float2bfloat16(f);
    return *(short*)&t;
}

__device__ __forceinline__ void load_edge(const int* __restrict__ ei, const int* __restrict__ yei,
                                          int e1, int e2, int e, int& src, int& dst) {
    if (e < e1) { src = ei[e]; dst = ei[e1 + e]; }
    else        { int t = e - e1; src = yei[t]; dst = yei[e2 + t]; }
}

// ---------------- prep: zero bcursor + build W fragments ----------------
__global__ void prep_k(const float* __restrict__ W, __hip_bfloat16* __restrict__ Wf,
                       int* __restrict__ bcursor) {
    int i = blockIdx.x * 256 + threadIdx.x;
    if (i < 1024) bcursor[i] = 0;
    int e = i - 1024;
    if (e >= 0 && e < INCH * LATD) {
        int k = e >> 5, c = e & 31;
        Wf[((k >> 3) * 32 + c) * 8 + (k & 7)] = __float2bfloat16(W[e]);
    }
}

// ---------------- gemmF: fused bucket-histogram + MFMA GEMM + dinv scale ----------------
__global__ __launch_bounds__(512) void gemm_fused_k(const float* __restrict__ x,
                                                    const __hip_bfloat16* __restrict__ Wf,
                                                    __hip_bfloat16* __restrict__ h,
                                                    const unsigned* __restrict__ bucketed,
                                                    const int* __restrict__ bcursor,
                                                    int* __restrict__ deg, int n) {
    __shared__ int cnt[BW];
    int tid = threadIdx.x;
    int b = blockIdx.x;
    int row0 = b << BSH;
    // issue x loads FIRST — they ride out HBM latency under the histogram phase
    int lane = tid & 63, wv = tid >> 6;
    int r = lane & 15, g = lane >> 4;
    int grow = row0 + (wv << 4) + r;
    bool rok = grow < n;
    const float4* xrow4 = (const float4*)(x + (size_t)grow * INCH + g * 8);
    float4 xa[8];
#pragma unroll
    for (int s = 0; s < 4; ++s) {
        if (rok) {
            xa[2 * s]     = xrow4[s * 8];
            xa[2 * s + 1] = xrow4[s * 8 + 1];
        } else {
            xa[2 * s]     = make_float4(0.f, 0.f, 0.f, 0.f);
            xa[2 * s + 1] = make_float4(0.f, 0.f, 0.f, 0.f);
        }
    }
    // phase 0: histogram this block's bucket -> cnt (degree of rows row0..row0+127)
    if (bucketed) {
        if (tid < BW) cnt[tid] = 0;
        __syncthreads();
        size_t s = (size_t)b * CAP;
        int tot = bcursor[b]; if (tot > CAP) tot = CAP;
        for (int i = tid; i < tot; i += 512)
            atomicAdd(&cnt[bucketed[s + i] & (BW - 1)], 1);
        __syncthreads();
        if (tid < BW) {
            int node = row0 + tid;
            if (node < n) deg[node] = cnt[tid];
        }
    }
    // phase 1: MFMA — wave wv owns rows row0+16*wv .. +15, cols 0..31 (2 tiles)
    const short* Wfb = (const short*)Wf;
    f32x4 acc0 = {0.f, 0.f, 0.f, 0.f};
    f32x4 acc1 = {0.f, 0.f, 0.f, 0.f};
#pragma unroll
    for (int s = 0; s < 4; ++s) {
        float4 a0 = xa[2 * s], a1 = xa[2 * s + 1];
        bf16x8 af;
        af[0] = f2bf(a0.x); af[1] = f2bf(a0.y); af[2] = f2bf(a0.z); af[3] = f2bf(a0.w);
        af[4] = f2bf(a1.x); af[5] = f2bf(a1.y); af[6] = f2bf(a1.z); af[7] = f2bf(a1.w);
        bf16x8 bf0 = *(const bf16x8*)(Wfb + (size_t)(((s * 4 + g) * 32) + r) * 8);
        bf16x8 bf1 = *(const bf16x8*)(Wfb + (size_t)(((s * 4 + g) * 32) + r + 16) * 8);
        acc0 = __builtin_amdgcn_mfma_f32_16x16x32_bf16(af, bf0, acc0, 0, 0, 0);
        acc1 = __builtin_amdgcn_mfma_f32_16x16x32_bf16(af, bf1, acc1, 0, 0, 0);
    }
#pragma unroll
    for (int i = 0; i < 4; ++i) {
        int rl = (wv << 4) + (g << 2) + i;
        int gr = row0 + rl;
        if (gr < n) {
            float dv = bucketed ? rsqrtf((float)cnt[rl] + 1.0f) : 1.0f;
            h[(size_t)gr * LATD + r]      = __float2bfloat16(acc0[i] * dv);
            h[(size_t)gr * LATD + r + 16] = __float2bfloat16(acc1[i] * dv);
        }
    }
}

__global__ void zero_i32_k(int* p, int cnt) {
    int i = blockIdx.x * 256 + threadIdx.x;
    if (i < cnt) p[i] = 0;
}

// ---------------- pass A: multisplit scatter, ACH=4096, wave-scan (R24 version) ----------------
__global__ __launch_bounds__(512) void passA_scatter_k(const int* __restrict__ ei, const int* __restrict__ yei,
                                                       int e1, int e2, int* __restrict__ bcursor,
                                                       unsigned* __restrict__ bucketed, int NB) {
    __shared__ int hist[1024];
    __shared__ int scanex[1024];
    __shared__ int segb[1024];
    __shared__ int wsum[8], wbase[8];
    __shared__ unsigned raw[ACH];
    __shared__ unsigned short rawb[ACH];
    __shared__ unsigned stage[ACH];
    __shared__ unsigned short bof[ACH];
    int tid = threadIdx.x;
    int E = e1 + e2;
    int e0 = blockIdx.x * ACH;
    int m = E - e0; if (m > ACH) m = ACH;
    for (int i = tid; i < 1024; i += 512) hist[i] = 0;
    __syncthreads();
    for (int i = tid; i < m; i += 512) {
        int src, dst; load_edge(ei, yei, e1, e2, e0 + i, src, dst);
        int b = dst >> BSH;
        raw[i]  = ((unsigned)src << BSH) | (unsigned)(dst & (BW - 1));
        rawb[i] = (unsigned short)b;
        atomicAdd(&hist[b], 1);
    }
    __syncthreads();
    int b2i = tid * 2;
    int c0 = hist[b2i], c1 = hist[b2i + 1];
    int pair = c0 + c1;
    int lane = tid & 63, wv = tid >> 6;
    int incl = pair;
#pragma unroll
    for (int off = 1; off < 64; off <<= 1) {
        int t = __shfl_up(incl, off);
        if (lane >= off) incl += t;
    }
    if (lane == 63) wsum[wv] = incl;
    __syncthreads();
    if (tid < 8) {
        int v = wsum[tid];
        int inc2 = v;
#pragma unroll
        for (int off = 1; off < 8; off <<= 1) {
            int t = __shfl_up(inc2, off);
            if (tid >= off) inc2 += t;
        }
        wbase[tid] = inc2 - v;
    }
    __syncthreads();
    int excl = wbase[wv] + incl - pair;
    scanex[b2i] = excl; scanex[b2i + 1] = excl + c0;
    __syncthreads();
    for (int b = tid; b < NB; b += 512)
        segb[b] = hist[b] ? atomicAdd(&bcursor[b], hist[b]) : 0;
    __syncthreads();
    for (int b = tid; b < 1024; b += 512) hist[b] = scanex[b];
    __syncthreads();
    for (int i = tid; i < m; i += 512) {
        unsigned pk = raw[i]; int b = rawb[i];
        int pos = atomicAdd(&hist[b], 1);
        stage[pos] = pk;
        bof[pos] = (unsigned short)b;
    }
    __syncthreads();
    for (int i = tid; i < m; i += 512) {
        int b = bof[i];
        int pos = segb[b] + (i - scanex[b]);
        if (pos < CAP)
            bucketed[(size_t)b * CAP + pos] = stage[i];
    }
}

// ---------------- B2: column-split (2 blocks/bucket); sort + per-node uint2 sweep ----------------
__global__ __launch_bounds__(512) void passB2_k(const unsigned* __restrict__ bucketed,
                                                const int* __restrict__ bcursor,
                                                const int* __restrict__ deg,
                                                const __hip_bfloat16* __restrict__ hs,
                                                const float* __restrict__ bias,
                                                float* __restrict__ out, int n) {
    __shared__ unsigned sorted[CAP];     // 16 KB
    __shared__ int cnt[BW], beg[BW], cur[BW];
    int tid = threadIdx.x;
    int b = blockIdx.x >> 1;             // bucket
    int p = blockIdx.x & 1;              // column half: cols [p*16, p*16+16)
    size_t s = (size_t)b * CAP;
    int tot = bcursor[b]; if (tot > CAP) tot = CAP;
    int dst0 = b << BSH;
    // register-stage the bucket (static indexing)
    unsigned ereg[8];
#pragma unroll
    for (int k = 0; k < 8; ++k) {
        int i = tid + (k << 9);
        ereg[k] = (i < tot) ? bucketed[s + i] : 0xFFFFFFFFu;
    }
    if (tid < BW) {
        int node = dst0 + tid;
        cnt[tid] = (node < n) ? deg[node] : 0;
    }
    __syncthreads();
    // wave-0 exclusive scan over 128 counts (2 per lane); save segment starts in beg[]
    if (tid < 64) {
        int b2 = tid * 2;
        int c0 = cnt[b2], c1 = cnt[b2 + 1];
        int pair = c0 + c1;
        int incl = pair;
#pragma unroll
        for (int off = 1; off < 64; off <<= 1) {
            int t = __shfl_up(incl, off);
            if (tid >= off) incl += t;
        }
        int excl = incl - pair;
        beg[b2] = excl;      beg[b2 + 1] = excl + c0;
        cur[b2] = excl;      cur[b2 + 1] = excl + c0;
    }
    __syncthreads();
    // counting-sort scatter from registers into LDS (duplicated across the p-pair)
#pragma unroll
    for (int k = 0; k < 8; ++k) {
        unsigned e = ereg[k];
        if (e != 0xFFFFFFFFu) {
            int pq = atomicAdd(&cur[e & (BW - 1)], 1);
            sorted[pq] = e;
        }
    }
    __syncthreads();
    // per-node sweep: group g (4 lanes) owns node g; this block covers 16 cols
    // (lane j -> cols p*16 + j*4 .. +3, uint2 gather = 4 cols). Branchless batch-8,
    // register accumulation, one float4 out-write with self+bias+dinv fused.
    const uint2* hsv = (const uint2*)hs;            // row stride = 8 uint2 (32 cols)
    int g = tid >> 2, j = tid & 3;
    int cw = p * 4 + j;                             // uint2 index within row (4 cols)
    int node = dst0 + g;
    int beg_ = beg[g];
    int cnt_ = cnt[g];
    float a0 = 0.f, a1 = 0.f, a2 = 0.f, a3 = 0.f;
    int i = 0;
    for (; i + 8 <= cnt_; i += 8) {
        unsigned pk8[8]; uint2 v8[8];
#pragma unroll
        for (int t = 0; t < 8; ++t) pk8[t] = sorted[beg_ + i + t];        // LDS broadcast
#pragma unroll
        for (int t = 0; t < 8; ++t) v8[t] = hsv[(size_t)(pk8[t] >> BSH) * 8 + cw];
#pragma unroll
        for (int t = 0; t < 8; ++t) {
            float2 f0 = __bfloat1622float2(*(__hip_bfloat162*)&v8[t].x);
            float2 f1 = __bfloat1622float2(*(__hip_bfloat162*)&v8[t].y);
            a0 += f0.x; a1 += f0.y; a2 += f1.x; a3 += f1.y;
        }
    }
#pragma unroll 4
    for (; i < cnt_; ++i) {
        unsigned pk = sorted[beg_ + i];
        uint2 v = hsv[(size_t)(pk >> BSH) * 8 + cw];
        float2 f0 = __bfloat1622float2(*(__hip_bfloat162*)&v.x);
        float2 f1 = __bfloat1622float2(*(__hip_bfloat162*)&v.y);
        a0 += f0.x; a1 += f0.y; a2 += f1.x; a3 += f1.y;
    }
    if (node < n) {
        float dv = rsqrtf((float)cnt_ + 1.0f);
        uint2 sv = hsv[(size_t)node * 8 + cw];                            // self (pre-scaled)
        float2 s0 = __bfloat1622float2(*(__hip_bfloat162*)&sv.x);
        float2 s1 = __bfloat1622float2(*(__hip_bfloat162*)&sv.y);
        float4 bv = *(const float4*)&bias[cw * 4];
        float4 o;
        o.x = (a0 + s0.x) * dv + bv.x;
        o.y = (a1 + s0.y) * dv + bv.y;
        o.z = (a2 + s1.x) * dv + bv.z;
        o.w = (a3 + s1.y) * dv + bv.w;
        *(float4*)&out[(size_t)node * LATD + cw * 4] = o;
    }
}

// ---------------- fallback path (atomic scatter; uses UNSCALED h) ----------------
__global__ void count_k(const int* __restrict__ ei, const int* __restrict__ yei,
                        int* __restrict__ cnt, int e1, int e2) {
    int e = blockIdx.x * 256 + threadIdx.x;
    if (e >= e1 + e2) return;
    int src, dst; load_edge(ei, yei, e1, e2, e, src, dst);
    atomicAdd(&cnt[dst], 1);
}

__global__ void dinv_k(const int* __restrict__ cnt, float* __restrict__ dinv, int n) {
    int i = blockIdx.x * 256 + threadIdx.x;
    if (i < n) dinv[i] = rsqrtf((float)cnt[i] + 1.0f);
}

__global__ void selfbias_k(const float* __restrict__ dinv, const __hip_bfloat16* __restrict__ h,
                           const float* __restrict__ b, float* __restrict__ out, int total) {
    int idx = blockIdx.x * 256 + threadIdx.x;
    if (idx >= total) return;
    int i = idx >> 5, j = idx & 31;
    float d = dinv[i];
    out[idx] = __bfloat162float(h[idx]) * d * d + b[j];
}

__global__ void scatter_atomic_k(const int* __restrict__ ei, const int* __restrict__ yei,
                                 const float* __restrict__ dinv, const __hip_bfloat16* __restrict__ h,
                                 float* __restrict__ out, int e1, int e2) {
    int idx = blockIdx.x * 256 + threadIdx.x;
    int e = idx >> 5;
    if (e >= e1 + e2) return;
    int j = idx & 31;
    int src, dst; load_edge(ei, yei, e1, e2, e, src, dst);
    float norm = dinv[src] * dinv[dst];
    atomicAdd(&out[(size_t)dst * LATD + j], __bfloat162float(h[(size_t)src * LATD + j]) * norm);
}

static inline size_t aln(size_t x) { return (x + 255) & ~(size_t)255; }

extern "C" void kernel_launch(void* const* d_in, const int* in_sizes, int n_in,
                              void* d_out, int out_size, void* d_ws, size_t ws_size,
                              hipStream_t stream) {
    const float* x  = (const float*)d_in[0];
    const int* ei   = (const int*)d_in[1];
    const int* yei  = (const int*)d_in[2];
    const float* W  = (const float*)d_in[3];
    const float* b  = (const float*)d_in[4];
    float* out = (float*)d_out;

    int n  = in_sizes[0] / INCH;
    int e1 = in_sizes[1] / 2;
    int e2 = in_sizes[2] / 2;
    int E  = e1 + e2;
    int NB = (n + BW - 1) >> BSH;

    char* p = (char*)d_ws;
    size_t off = 0;
    float* dinv = (float*)(p + off);            off += aln((size_t)n * 4);
    __hip_bfloat16* h = (__hip_bfloat16*)(p + off); off += aln((size_t)n * LATD * 2);
    unsigned* bucketed = (unsigned*)(p + off);  size_t bucketed_off = off; off += aln((size_t)NB * CAP * 4);
    int* bcursor = (int*)(p + off);             off += aln((size_t)(1024 + n) * 4);
    int* deg = bcursor + 1024;
    __hip_bfloat16* Wf = (__hip_bfloat16*)(p + off); off += aln((size_t)INCH * LATD * 2);
    bool fast_ok = (off <= ws_size) && (NB <= 1024);

    if (fast_ok) {
        int ablocks = (E + ACH - 1) / ACH;
        prep_k<<<20, 256, 0, stream>>>(W, Wf, bcursor);
        passA_scatter_k<<<ablocks, 512, 0, stream>>>(ei, yei, e1, e2, bcursor, bucketed, NB);
        gemm_fused_k<<<NB, 512, 0, stream>>>(x, Wf, h, bucketed, bcursor, deg, n);  // hist+MFMA+scale
        passB2_k<<<NB * 2, 512, 0, stream>>>(bucketed, bcursor, deg, h, b, out, n); // 2 blocks/bucket
    } else {
        prep_k<<<20, 256, 0, stream>>>(W, Wf, bcursor);
        gemm_fused_k<<<(n + 127) / 128, 512, 0, stream>>>(x, Wf, h, nullptr, nullptr, nullptr, n); // unscaled
        int* cntf = (int*)(p + bucketed_off);
        zero_i32_k<<<(n + 255) / 256, 256, 0, stream>>>(cntf, n);
        count_k<<<(E + 255) / 256, 256, 0, stream>>>(ei, yei, cntf, e1, e2);
        dinv_k<<<(n + 255) / 256, 256, 0, stream>>>(cntf, dinv, n);
        selfbias_k<<<(out_size + 255) / 256, 256, 0, stream>>>(dinv, h, b, out, out_size);
        scatter_atomic_k<<<((size_t)E * LATD + 255) / 256, 256, 0, stream>>>(ei, yei, dinv, h, out, e1, e2);
    }
}

// Round 13
// 153.442 us; speedup vs baseline: 1.0874x; 1.0874x over previous
//
#include <hip/hip_runtime.h>
#include <hip/hip_bf16.h>

// GCNConv encoder — R27 = R24 (best, 150.8us) + segb-stagger in passA.
//   prep:   zero bcursor + pre-swizzle W into MFMA B-fragment order (bf16, 8KB)
//   passA:  single-read multisplit, ACH=4096, 60KB LDS [R24] + P3 bucket loop starts
//           at (blockIdx*331)%NB: decorrelates the ~516k device-scope bcursor atomics
//           (64 cache lines) across blocks — R26 showed cross-XCD same-line bursts
//           serialize at L3.
//   gemmF:  MFMA gemm + fused bucket-histogram + *rsqrt(deg+1), x-loads hoisted [R24]
//   B2:     counting sort + per-node 4-lane uint4 branchless sweep [R24].
//           R26 column-split REVERTED: +16us — doubling stage+sort front-matter and
//           duplicating gather lines across XCD L2s loses; sweep is gather-service
//           bound, not latency-bound.
// LESSONS: per-edge ordered LDS ops in gather loop = serial chain (R15/16, 433us);
//          per-edge random global atomics = +60MB writes (R18, 103us);
//          divergent per-edge branches serialize the wave (R22->R23);
//          compiler splits >8-deep gather batches (R22, VGPR=36);
//          passA double-read not L2-warm (R25); B2 block-split loses (R26).
//
// Fragment layouts (learn_hip m89/m92-verified):
//   A: row = lane&15, k = 8*(lane>>4)+i (contiguous)   B: col = lane&15, same k-group
//   C/D: col = lane&15, row = 4*(lane>>4)+reg
//
// ws: dinv[n] f32 (fallback) | h[n*32] bf16 | bucketed[NB*CAP] u32 | bcursor[1024]+deg[n] | Wf[4096] bf16

#define LATD 32
#define INCH 128
#define BSH 7
#define BW 128
#define CAP 4096
#define ACH 4096

typedef short bf16x8 __attribute__((ext_vector_type(8)));   // 8 bf16 in 4 VGPRs
typedef float f32x4 __attribute__((ext_vector_type(4)));

__device__ __forceinline__ short f2bf(float f) {
    __hip_bfloat16 t = __float2bfloat16(f);
    return *(short*)&t;
}

__device__ __forceinline__ void load_edge(const int* __restrict__ ei, const int* __restrict__ yei,
                                          int e1, int e2, int e, int& src, int& dst) {
    if (e < e1) { src = ei[e]; dst = ei[e1 + e]; }
    else        { int t = e - e1; src = yei[t]; dst = yei[e2 + t]; }
}

// ---------------- prep: zero bcursor + build W fragments ----------------
__global__ void prep_k(const float* __restrict__ W, __hip_bfloat16* __restrict__ Wf,
                       int* __restrict__ bcursor) {
    int i = blockIdx.x * 256 + threadIdx.x;
    if (i < 1024) bcursor[i] = 0;
    int e = i - 1024;
    if (e >= 0 && e < INCH * LATD) {
        int k = e >> 5, c = e & 31;
        Wf[((k >> 3) * 32 + c) * 8 + (k & 7)] = __float2bfloat16(W[e]);
    }
}

// ---------------- gemmF: fused bucket-histogram + MFMA GEMM + dinv scale ----------------
__global__ __launch_bounds__(512) void gemm_fused_k(const float* __restrict__ x,
                                                    const __hip_bfloat16* __restrict__ Wf,
                                                    __hip_bfloat16* __restrict__ h,
                                                    const unsigned* __restrict__ bucketed,
                                                    const int* __restrict__ bcursor,
                                                    int* __restrict__ deg, int n) {
    __shared__ int cnt[BW];
    int tid = threadIdx.x;
    int b = blockIdx.x;
    int row0 = b << BSH;
    // issue x loads FIRST — they ride out HBM latency under the histogram phase
    int lane = tid & 63, wv = tid >> 6;
    int r = lane & 15, g = lane >> 4;
    int grow = row0 + (wv << 4) + r;
    bool rok = grow < n;
    const float4* xrow4 = (const float4*)(x + (size_t)grow * INCH + g * 8);
    float4 xa[8];
#pragma unroll
    for (int s = 0; s < 4; ++s) {
        if (rok) {
            xa[2 * s]     = xrow4[s * 8];
            xa[2 * s + 1] = xrow4[s * 8 + 1];
        } else {
            xa[2 * s]     = make_float4(0.f, 0.f, 0.f, 0.f);
            xa[2 * s + 1] = make_float4(0.f, 0.f, 0.f, 0.f);
        }
    }
    // phase 0: histogram this block's bucket -> cnt (degree of rows row0..row0+127)
    if (bucketed) {
        if (tid < BW) cnt[tid] = 0;
        __syncthreads();
        size_t s = (size_t)b * CAP;
        int tot = bcursor[b]; if (tot > CAP) tot = CAP;
        for (int i = tid; i < tot; i += 512)
            atomicAdd(&cnt[bucketed[s + i] & (BW - 1)], 1);
        __syncthreads();
        if (tid < BW) {
            int node = row0 + tid;
            if (node < n) deg[node] = cnt[tid];
        }
    }
    // phase 1: MFMA — wave wv owns rows row0+16*wv .. +15, cols 0..31 (2 tiles)
    const short* Wfb = (const short*)Wf;
    f32x4 acc0 = {0.f, 0.f, 0.f, 0.f};
    f32x4 acc1 = {0.f, 0.f, 0.f, 0.f};
#pragma unroll
    for (int s = 0; s < 4; ++s) {
        float4 a0 = xa[2 * s], a1 = xa[2 * s + 1];
        bf16x8 af;
        af[0] = f2bf(a0.x); af[1] = f2bf(a0.y); af[2] = f2bf(a0.z); af[3] = f2bf(a0.w);
        af[4] = f2bf(a1.x); af[5] = f2bf(a1.y); af[6] = f2bf(a1.z); af[7] = f2bf(a1.w);
        bf16x8 bf0 = *(const bf16x8*)(Wfb + (size_t)(((s * 4 + g) * 32) + r) * 8);
        bf16x8 bf1 = *(const bf16x8*)(Wfb + (size_t)(((s * 4 + g) * 32) + r + 16) * 8);
        acc0 = __builtin_amdgcn_mfma_f32_16x16x32_bf16(af, bf0, acc0, 0, 0, 0);
        acc1 = __builtin_amdgcn_mfma_f32_16x16x32_bf16(af, bf1, acc1, 0, 0, 0);
    }
#pragma unroll
    for (int i = 0; i < 4; ++i) {
        int rl = (wv << 4) + (g << 2) + i;
        int gr = row0 + rl;
        if (gr < n) {
            float dv = bucketed ? rsqrtf((float)cnt[rl] + 1.0f) : 1.0f;
            h[(size_t)gr * LATD + r]      = __float2bfloat16(acc0[i] * dv);
            h[(size_t)gr * LATD + r + 16] = __float2bfloat16(acc1[i] * dv);
        }
    }
}

__global__ void zero_i32_k(int* p, int cnt) {
    int i = blockIdx.x * 256 + threadIdx.x;
    if (i < cnt) p[i] = 0;
}

// ---------------- pass A: multisplit scatter, ACH=4096, wave-scan, staggered segb ----------------
__global__ __launch_bounds__(512) void passA_scatter_k(const int* __restrict__ ei, const int* __restrict__ yei,
                                                       int e1, int e2, int* __restrict__ bcursor,
                                                       unsigned* __restrict__ bucketed, int NB) {
    __shared__ int hist[1024];
    __shared__ int scanex[1024];
    __shared__ int segb[1024];
    __shared__ int wsum[8], wbase[8];
    __shared__ unsigned raw[ACH];
    __shared__ unsigned short rawb[ACH];
    __shared__ unsigned stage[ACH];
    __shared__ unsigned short bof[ACH];
    int tid = threadIdx.x;
    int E = e1 + e2;
    int e0 = blockIdx.x * ACH;
    int m = E - e0; if (m > ACH) m = ACH;
    for (int i = tid; i < 1024; i += 512) hist[i] = 0;
    __syncthreads();
    for (int i = tid; i < m; i += 512) {
        int src, dst; load_edge(ei, yei, e1, e2, e0 + i, src, dst);
        int b = dst >> BSH;
        raw[i]  = ((unsigned)src << BSH) | (unsigned)(dst & (BW - 1));
        rawb[i] = (unsigned short)b;
        atomicAdd(&hist[b], 1);
    }
    __syncthreads();
    int b2i = tid * 2;
    int c0 = hist[b2i], c1 = hist[b2i + 1];
    int pair = c0 + c1;
    int lane = tid & 63, wv = tid >> 6;
    int incl = pair;
#pragma unroll
    for (int off = 1; off < 64; off <<= 1) {
        int t = __shfl_up(incl, off);
        if (lane >= off) incl += t;
    }
    if (lane == 63) wsum[wv] = incl;
    __syncthreads();
    if (tid < 8) {
        int v = wsum[tid];
        int inc2 = v;
#pragma unroll
        for (int off = 1; off < 8; off <<= 1) {
            int t = __shfl_up(inc2, off);
            if (tid >= off) inc2 += t;
        }
        wbase[tid] = inc2 - v;
    }
    __syncthreads();
    int excl = wbase[wv] + incl - pair;
    scanex[b2i] = excl; scanex[b2i + 1] = excl + c0;
    __syncthreads();
    // P3: reserve global bucket segments — start at a per-block rotation so blocks
    // hit DIFFERENT bcursor cache lines at any instant (cross-XCD same-line atomic
    // bursts serialize at L3)
    {
        int start = (blockIdx.x * 331) % NB;
        for (int bb = tid; bb < NB; bb += 512) {
            int b = bb + start; if (b >= NB) b -= NB;
            segb[b] = hist[b] ? atomicAdd(&bcursor[b], hist[b]) : 0;
        }
    }
    __syncthreads();
    for (int b = tid; b < 1024; b += 512) hist[b] = scanex[b];
    __syncthreads();
    for (int i = tid; i < m; i += 512) {
        unsigned pk = raw[i]; int b = rawb[i];
        int pos = atomicAdd(&hist[b], 1);
        stage[pos] = pk;
        bof[pos] = (unsigned short)b;
    }
    __syncthreads();
    for (int i = tid; i < m; i += 512) {
        int b = bof[i];
        int pos = segb[b] + (i - scanex[b]);
        if (pos < CAP)
            bucketed[(size_t)b * CAP + pos] = stage[i];
    }
}

// ---------------- B2: sort + per-node 4-lane uint4 sweep; direct out writes ----------------
__global__ __launch_bounds__(512) void passB2_k(const unsigned* __restrict__ bucketed,
                                                const int* __restrict__ bcursor,
                                                const int* __restrict__ deg,
                                                const __hip_bfloat16* __restrict__ hs,
                                                const float* __restrict__ bias,
                                                float* __restrict__ out, int n) {
    __shared__ unsigned sorted[CAP];     // 16 KB
    __shared__ int cnt[BW], beg[BW], cur[BW];
    int tid = threadIdx.x;
    int b = blockIdx.x;
    size_t s = (size_t)b * CAP;
    int tot = bcursor[b]; if (tot > CAP) tot = CAP;
    int dst0 = b << BSH;
    // register-stage the bucket (static indexing)
    unsigned ereg[8];
#pragma unroll
    for (int k = 0; k < 8; ++k) {
        int i = tid + (k << 9);
        ereg[k] = (i < tot) ? bucketed[s + i] : 0xFFFFFFFFu;
    }
    if (tid < BW) {
        int node = dst0 + tid;
        cnt[tid] = (node < n) ? deg[node] : 0;
    }
    __syncthreads();
    // wave-0 exclusive scan over 128 counts (2 per lane); save segment starts in beg[]
    if (tid < 64) {
        int b2 = tid * 2;
        int c0 = cnt[b2], c1 = cnt[b2 + 1];
        int pair = c0 + c1;
        int incl = pair;
#pragma unroll
        for (int off = 1; off < 64; off <<= 1) {
            int t = __shfl_up(incl, off);
            if (tid >= off) incl += t;
        }
        int excl = incl - pair;
        beg[b2] = excl;      beg[b2 + 1] = excl + c0;
        cur[b2] = excl;      cur[b2 + 1] = excl + c0;
    }
    __syncthreads();
    // counting-sort scatter from registers into LDS
#pragma unroll
    for (int k = 0; k < 8; ++k) {
        unsigned e = ereg[k];
        if (e != 0xFFFFFFFFu) {
            int p = atomicAdd(&cur[e & (BW - 1)], 1);
            sorted[p] = e;
        }
    }
    __syncthreads();
    // per-node sweep: group g (4 lanes, j = 8-col slice) owns node g (128 groups).
    // Branchless batch-8 uint4 gathers, register accumulation, direct out-writes with
    // self+bias+dinv fused.
    const uint4* hsv = (const uint4*)hs;            // row stride = 4 uint4
    int g = tid >> 2, j = tid & 3;
    int node = dst0 + g;
    int beg_ = beg[g];
    int cnt_ = cnt[g];
    float a0 = 0.f, a1 = 0.f, a2 = 0.f, a3 = 0.f;
    float a4 = 0.f, a5 = 0.f, a6 = 0.f, a7 = 0.f;
    int i = 0;
    for (; i + 8 <= cnt_; i += 8) {
        unsigned pk8[8]; uint4 v8[8];
#pragma unroll
        for (int t = 0; t < 8; ++t) pk8[t] = sorted[beg_ + i + t];        // LDS broadcast
#pragma unroll
        for (int t = 0; t < 8; ++t) v8[t] = hsv[(size_t)(pk8[t] >> BSH) * 4 + j];
#pragma unroll
        for (int t = 0; t < 8; ++t) {
            float2 f0 = __bfloat1622float2(*(__hip_bfloat162*)&v8[t].x);
            float2 f1 = __bfloat1622float2(*(__hip_bfloat162*)&v8[t].y);
            float2 f2 = __bfloat1622float2(*(__hip_bfloat162*)&v8[t].z);
            float2 f3 = __bfloat1622float2(*(__hip_bfloat162*)&v8[t].w);
            a0 += f0.x; a1 += f0.y; a2 += f1.x; a3 += f1.y;
            a4 += f2.x; a5 += f2.y; a6 += f3.x; a7 += f3.y;
        }
    }
#pragma unroll 4
    for (; i < cnt_; ++i) {
        unsigned pk = sorted[beg_ + i];
        uint4 v = hsv[(size_t)(pk >> BSH) * 4 + j];
        float2 f0 = __bfloat1622float2(*(__hip_bfloat162*)&v.x);
        float2 f1 = __bfloat1622float2(*(__hip_bfloat162*)&v.y);
        float2 f2 = __bfloat1622float2(*(__hip_bfloat162*)&v.z);
        float2 f3 = __bfloat1622float2(*(__hip_bfloat162*)&v.w);
        a0 += f0.x; a1 += f0.y; a2 += f1.x; a3 += f1.y;
        a4 += f2.x; a5 += f2.y; a6 += f3.x; a7 += f3.y;
    }
    if (node < n) {
        float dv = rsqrtf((float)cnt_ + 1.0f);
        uint4 sv = hsv[(size_t)node * 4 + j];                             // self (pre-scaled)
        float2 s0 = __bfloat1622float2(*(__hip_bfloat162*)&sv.x);
        float2 s1 = __bfloat1622float2(*(__hip_bfloat162*)&sv.y);
        float2 s2 = __bfloat1622float2(*(__hip_bfloat162*)&sv.z);
        float2 s3 = __bfloat1622float2(*(__hip_bfloat162*)&sv.w);
        float4 bv0 = *(const float4*)&bias[j * 8];
        float4 bv1 = *(const float4*)&bias[j * 8 + 4];
        float4 o0, o1;
        o0.x = (a0 + s0.x) * dv + bv0.x;
        o0.y = (a1 + s0.y) * dv + bv0.y;
        o0.z = (a2 + s1.x) * dv + bv0.z;
        o0.w = (a3 + s1.y) * dv + bv0.w;
        o1.x = (a4 + s2.x) * dv + bv1.x;
        o1.y = (a5 + s2.y) * dv + bv1.y;
        o1.z = (a6 + s3.x) * dv + bv1.z;
        o1.w = (a7 + s3.y) * dv + bv1.w;
        *(float4*)&out[(size_t)node * LATD + j * 8]     = o0;
        *(float4*)&out[(size_t)node * LATD + j * 8 + 4] = o1;
    }
}

// ---------------- fallback path (atomic scatter; uses UNSCALED h) ----------------
__global__ void count_k(const int* __restrict__ ei, const int* __restrict__ yei,
                        int* __restrict__ cnt, int e1, int e2) {
    int e = blockIdx.x * 256 + threadIdx.x;
    if (e >= e1 + e2) return;
    int src, dst; load_edge(ei, yei, e1, e2, e, src, dst);
    atomicAdd(&cnt[dst], 1);
}

__global__ void dinv_k(const int* __restrict__ cnt, float* __restrict__ dinv, int n) {
    int i = blockIdx.x * 256 + threadIdx.x;
    if (i < n) dinv[i] = rsqrtf((float)cnt[i] + 1.0f);
}

__global__ void selfbias_k(const float* __restrict__ dinv, const __hip_bfloat16* __restrict__ h,
                           const float* __restrict__ b, float* __restrict__ out, int total) {
    int idx = blockIdx.x * 256 + threadIdx.x;
    if (idx >= total) return;
    int i = idx >> 5, j = idx & 31;
    float d = dinv[i];
    out[idx] = __bfloat162float(h[idx]) * d * d + b[j];
}

__global__ void scatter_atomic_k(const int* __restrict__ ei, const int* __restrict__ yei,
                                 const float* __restrict__ dinv, const __hip_bfloat16* __restrict__ h,
                                 float* __restrict__ out, int e1, int e2) {
    int idx = blockIdx.x * 256 + threadIdx.x;
    int e = idx >> 5;
    if (e >= e1 + e2) return;
    int j = idx & 31;
    int src, dst; load_edge(ei, yei, e1, e2, e, src, dst);
    float norm = dinv[src] * dinv[dst];
    atomicAdd(&out[(size_t)dst * LATD + j], __bfloat162float(h[(size_t)src * LATD + j]) * norm);
}

static inline size_t aln(size_t x) { return (x + 255) & ~(size_t)255; }

extern "C" void kernel_launch(void* const* d_in, const int* in_sizes, int n_in,
                              void* d_out, int out_size, void* d_ws, size_t ws_size,
                              hipStream_t stream) {
    const float* x  = (const float*)d_in[0];
    const int* ei   = (const int*)d_in[1];
    const int* yei  = (const int*)d_in[2];
    const float* W  = (const float*)d_in[3];
    const float* b  = (const float*)d_in[4];
    float* out = (float*)d_out;

    int n  = in_sizes[0] / INCH;
    int e1 = in_sizes[1] / 2;
    int e2 = in_sizes[2] / 2;
    int E  = e1 + e2;
    int NB = (n + BW - 1) >> BSH;

    char* p = (char*)d_ws;
    size_t off = 0;
    float* dinv = (float*)(p + off);            off += aln((size_t)n * 4);
    __hip_bfloat16* h = (__hip_bfloat16*)(p + off); off += aln((size_t)n * LATD * 2);
    unsigned* bucketed = (unsigned*)(p + off);  size_t bucketed_off = off; off += aln((size_t)NB * CAP * 4);
    int* bcursor = (int*)(p + off);             off += aln((size_t)(1024 + n) * 4);
    int* deg = bcursor + 1024;
    __hip_bfloat16* Wf = (__hip_bfloat16*)(p + off); off += aln((size_t)INCH * LATD * 2);
    bool fast_ok = (off <= ws_size) && (NB <= 1024);

    if (fast_ok) {
        int ablocks = (E + ACH - 1) / ACH;
        prep_k<<<20, 256, 0, stream>>>(W, Wf, bcursor);
        passA_scatter_k<<<ablocks, 512, 0, stream>>>(ei, yei, e1, e2, bcursor, bucketed, NB);
        gemm_fused_k<<<NB, 512, 0, stream>>>(x, Wf, h, bucketed, bcursor, deg, n);  // hist+MFMA+scale
        passB2_k<<<NB, 512, 0, stream>>>(bucketed, bcursor, deg, h, b, out, n);
    } else {
        prep_k<<<20, 256, 0, stream>>>(W, Wf, bcursor);
        gemm_fused_k<<<(n + 127) / 128, 512, 0, stream>>>(x, Wf, h, nullptr, nullptr, nullptr, n); // unscaled
        int* cntf = (int*)(p + bucketed_off);
        zero_i32_k<<<(n + 255) / 256, 256, 0, stream>>>(cntf, n);
        count_k<<<(E + 255) / 256, 256, 0, stream>>>(ei, yei, cntf, e1, e2);
        dinv_k<<<(n + 255) / 256, 256, 0, stream>>>(cntf, dinv, n);
        selfbias_k<<<(out_size + 255) / 256, 256, 0, stream>>>(dinv, h, b, out, out_size);
        scatter_atomic_k<<<((size_t)E * LATD + 255) / 256, 256, 0, stream>>>(ei, yei, dinv, h, out, e1, e2);
    }
}

// Round 14
// 152.580 us; speedup vs baseline: 1.0935x; 1.0056x over previous
//
#include <hip/hip_runtime.h>
#include <hip/hip_bf16.h>

// GCNConv encoder — R28 = exact R24 revert (session best, 150.8us).
//   prep:   zero bcursor + pre-swizzle W into MFMA B-fragment order (bf16, 8KB)
//   passA:  single-read multisplit, ACH=4096, 60KB LDS, wave-scan
//   gemmF:  MFMA gemm (16x16x32 bf16) + fused bucket-histogram + *rsqrt(deg+1),
//           x-loads hoisted above the hist phase
//   B2:     counting sort + per-node 4-lane uint4 branchless sweep, fused
//           (neigh+self)*dinv+bias float4 store
// Session ledger: 190.4 -> 150.8 (-21%). Failed structural attempts (all reverted):
//   R15/16 per-edge LDS atomics in gather loop (433us, serial chain);
//   R18 per-edge global atomic degree count (+60MB writes, 103us passA);
//   R22 segmented-sweep divergent flush (43us B2; fixed by per-node sweep R23);
//   R25 passA double-read (not L2-warm cross-XCD, +2.8);
//   R26 B2 column-split (stage+sort duplication, +16);
//   R27 bcursor stagger (neutral/slightly negative, +2.6).
// Remaining kernels all <41us each, <=21% HBM, <=28% VALU — latency/front-matter
// floor for this decomposition.
//
// Fragment layouts (learn_hip m89/m92-verified):
//   A: row = lane&15, k = 8*(lane>>4)+i (contiguous)   B: col = lane&15, same k-group
//   C/D: col = lane&15, row = 4*(lane>>4)+reg
//
// ws: dinv[n] f32 (fallback) | h[n*32] bf16 | bucketed[NB*CAP] u32 | bcursor[1024]+deg[n] | Wf[4096] bf16

#define LATD 32
#define INCH 128
#define BSH 7
#define BW 128
#define CAP 4096
#define ACH 4096

typedef short bf16x8 __attribute__((ext_vector_type(8)));   // 8 bf16 in 4 VGPRs
typedef float f32x4 __attribute__((ext_vector_type(4)));

__device__ __forceinline__ short f2bf(float f) {
    __hip_bfloat16 t = __float2bfloat16(f);
    return *(short*)&t;
}

__device__ __forceinline__ void load_edge(const int* __restrict__ ei, const int* __restrict__ yei,
                                          int e1, int e2, int e, int& src, int& dst) {
    if (e < e1) { src = ei[e]; dst = ei[e1 + e]; }
    else        { int t = e - e1; src = yei[t]; dst = yei[e2 + t]; }
}

// ---------------- prep: zero bcursor + build W fragments ----------------
__global__ void prep_k(const float* __restrict__ W, __hip_bfloat16* __restrict__ Wf,
                       int* __restrict__ bcursor) {
    int i = blockIdx.x * 256 + threadIdx.x;
    if (i < 1024) bcursor[i] = 0;
    int e = i - 1024;
    if (e >= 0 && e < INCH * LATD) {
        int k = e >> 5, c = e & 31;
        Wf[((k >> 3) * 32 + c) * 8 + (k & 7)] = __float2bfloat16(W[e]);
    }
}

// ---------------- gemmF: fused bucket-histogram + MFMA GEMM + dinv scale ----------------
__global__ __launch_bounds__(512) void gemm_fused_k(const float* __restrict__ x,
                                                    const __hip_bfloat16* __restrict__ Wf,
                                                    __hip_bfloat16* __restrict__ h,
                                                    const unsigned* __restrict__ bucketed,
                                                    const int* __restrict__ bcursor,
                                                    int* __restrict__ deg, int n) {
    __shared__ int cnt[BW];
    int tid = threadIdx.x;
    int b = blockIdx.x;
    int row0 = b << BSH;
    // issue x loads FIRST — they ride out HBM latency under the histogram phase
    int lane = tid & 63, wv = tid >> 6;
    int r = lane & 15, g = lane >> 4;
    int grow = row0 + (wv << 4) + r;
    bool rok = grow < n;
    const float4* xrow4 = (const float4*)(x + (size_t)grow * INCH + g * 8);
    float4 xa[8];
#pragma unroll
    for (int s = 0; s < 4; ++s) {
        if (rok) {
            xa[2 * s]     = xrow4[s * 8];
            xa[2 * s + 1] = xrow4[s * 8 + 1];
        } else {
            xa[2 * s]     = make_float4(0.f, 0.f, 0.f, 0.f);
            xa[2 * s + 1] = make_float4(0.f, 0.f, 0.f, 0.f);
        }
    }
    // phase 0: histogram this block's bucket -> cnt (degree of rows row0..row0+127)
    if (bucketed) {
        if (tid < BW) cnt[tid] = 0;
        __syncthreads();
        size_t s = (size_t)b * CAP;
        int tot = bcursor[b]; if (tot > CAP) tot = CAP;
        for (int i = tid; i < tot; i += 512)
            atomicAdd(&cnt[bucketed[s + i] & (BW - 1)], 1);
        __syncthreads();
        if (tid < BW) {
            int node = row0 + tid;
            if (node < n) deg[node] = cnt[tid];
        }
    }
    // phase 1: MFMA — wave wv owns rows row0+16*wv .. +15, cols 0..31 (2 tiles)
    const short* Wfb = (const short*)Wf;
    f32x4 acc0 = {0.f, 0.f, 0.f, 0.f};
    f32x4 acc1 = {0.f, 0.f, 0.f, 0.f};
#pragma unroll
    for (int s = 0; s < 4; ++s) {
        float4 a0 = xa[2 * s], a1 = xa[2 * s + 1];
        bf16x8 af;
        af[0] = f2bf(a0.x); af[1] = f2bf(a0.y); af[2] = f2bf(a0.z); af[3] = f2bf(a0.w);
        af[4] = f2bf(a1.x); af[5] = f2bf(a1.y); af[6] = f2bf(a1.z); af[7] = f2bf(a1.w);
        bf16x8 bf0 = *(const bf16x8*)(Wfb + (size_t)(((s * 4 + g) * 32) + r) * 8);
        bf16x8 bf1 = *(const bf16x8*)(Wfb + (size_t)(((s * 4 + g) * 32) + r + 16) * 8);
        acc0 = __builtin_amdgcn_mfma_f32_16x16x32_bf16(af, bf0, acc0, 0, 0, 0);
        acc1 = __builtin_amdgcn_mfma_f32_16x16x32_bf16(af, bf1, acc1, 0, 0, 0);
    }
#pragma unroll
    for (int i = 0; i < 4; ++i) {
        int rl = (wv << 4) + (g << 2) + i;
        int gr = row0 + rl;
        if (gr < n) {
            float dv = bucketed ? rsqrtf((float)cnt[rl] + 1.0f) : 1.0f;
            h[(size_t)gr * LATD + r]      = __float2bfloat16(acc0[i] * dv);
            h[(size_t)gr * LATD + r + 16] = __float2bfloat16(acc1[i] * dv);
        }
    }
}

__global__ void zero_i32_k(int* p, int cnt) {
    int i = blockIdx.x * 256 + threadIdx.x;
    if (i < cnt) p[i] = 0;
}

// ---------------- pass A: multisplit scatter, ACH=4096, wave-scan ----------------
__global__ __launch_bounds__(512) void passA_scatter_k(const int* __restrict__ ei, const int* __restrict__ yei,
                                                       int e1, int e2, int* __restrict__ bcursor,
                                                       unsigned* __restrict__ bucketed, int NB) {
    __shared__ int hist[1024];
    __shared__ int scanex[1024];
    __shared__ int segb[1024];
    __shared__ int wsum[8], wbase[8];
    __shared__ unsigned raw[ACH];
    __shared__ unsigned short rawb[ACH];
    __shared__ unsigned stage[ACH];
    __shared__ unsigned short bof[ACH];
    int tid = threadIdx.x;
    int E = e1 + e2;
    int e0 = blockIdx.x * ACH;
    int m = E - e0; if (m > ACH) m = ACH;
    for (int i = tid; i < 1024; i += 512) hist[i] = 0;
    __syncthreads();
    for (int i = tid; i < m; i += 512) {
        int src, dst; load_edge(ei, yei, e1, e2, e0 + i, src, dst);
        int b = dst >> BSH;
        raw[i]  = ((unsigned)src << BSH) | (unsigned)(dst & (BW - 1));
        rawb[i] = (unsigned short)b;
        atomicAdd(&hist[b], 1);
    }
    __syncthreads();
    int b2i = tid * 2;
    int c0 = hist[b2i], c1 = hist[b2i + 1];
    int pair = c0 + c1;
    int lane = tid & 63, wv = tid >> 6;
    int incl = pair;
#pragma unroll
    for (int off = 1; off < 64; off <<= 1) {
        int t = __shfl_up(incl, off);
        if (lane >= off) incl += t;
    }
    if (lane == 63) wsum[wv] = incl;
    __syncthreads();
    if (tid < 8) {
        int v = wsum[tid];
        int inc2 = v;
#pragma unroll
        for (int off = 1; off < 8; off <<= 1) {
            int t = __shfl_up(inc2, off);
            if (tid >= off) inc2 += t;
        }
        wbase[tid] = inc2 - v;
    }
    __syncthreads();
    int excl = wbase[wv] + incl - pair;
    scanex[b2i] = excl; scanex[b2i + 1] = excl + c0;
    __syncthreads();
    for (int b = tid; b < NB; b += 512)
        segb[b] = hist[b] ? atomicAdd(&bcursor[b], hist[b]) : 0;
    __syncthreads();
    for (int b = tid; b < 1024; b += 512) hist[b] = scanex[b];
    __syncthreads();
    for (int i = tid; i < m; i += 512) {
        unsigned pk = raw[i]; int b = rawb[i];
        int pos = atomicAdd(&hist[b], 1);
        stage[pos] = pk;
        bof[pos] = (unsigned short)b;
    }
    __syncthreads();
    for (int i = tid; i < m; i += 512) {
        int b = bof[i];
        int pos = segb[b] + (i - scanex[b]);
        if (pos < CAP)
            bucketed[(size_t)b * CAP + pos] = stage[i];
    }
}

// ---------------- B2: sort + per-node 4-lane uint4 sweep; direct out writes ----------------
__global__ __launch_bounds__(512) void passB2_k(const unsigned* __restrict__ bucketed,
                                                const int* __restrict__ bcursor,
                                                const int* __restrict__ deg,
                                                const __hip_bfloat16* __restrict__ hs,
                                                const float* __restrict__ bias,
                                                float* __restrict__ out, int n) {
    __shared__ unsigned sorted[CAP];     // 16 KB
    __shared__ int cnt[BW], beg[BW], cur[BW];
    int tid = threadIdx.x;
    int b = blockIdx.x;
    size_t s = (size_t)b * CAP;
    int tot = bcursor[b]; if (tot > CAP) tot = CAP;
    int dst0 = b << BSH;
    // register-stage the bucket (static indexing)
    unsigned ereg[8];
#pragma unroll
    for (int k = 0; k < 8; ++k) {
        int i = tid + (k << 9);
        ereg[k] = (i < tot) ? bucketed[s + i] : 0xFFFFFFFFu;
    }
    if (tid < BW) {
        int node = dst0 + tid;
        cnt[tid] = (node < n) ? deg[node] : 0;
    }
    __syncthreads();
    // wave-0 exclusive scan over 128 counts (2 per lane); save segment starts in beg[]
    if (tid < 64) {
        int b2 = tid * 2;
        int c0 = cnt[b2], c1 = cnt[b2 + 1];
        int pair = c0 + c1;
        int incl = pair;
#pragma unroll
        for (int off = 1; off < 64; off <<= 1) {
            int t = __shfl_up(incl, off);
            if (tid >= off) incl += t;
        }
        int excl = incl - pair;
        beg[b2] = excl;      beg[b2 + 1] = excl + c0;
        cur[b2] = excl;      cur[b2 + 1] = excl + c0;
    }
    __syncthreads();
    // counting-sort scatter from registers into LDS
#pragma unroll
    for (int k = 0; k < 8; ++k) {
        unsigned e = ereg[k];
        if (e != 0xFFFFFFFFu) {
            int p = atomicAdd(&cur[e & (BW - 1)], 1);
            sorted[p] = e;
        }
    }
    __syncthreads();
    // per-node sweep: group g (4 lanes, j = 8-col slice) owns node g (128 groups).
    // Branchless batch-8 uint4 gathers, register accumulation, direct out-writes with
    // self+bias+dinv fused.
    const uint4* hsv = (const uint4*)hs;            // row stride = 4 uint4
    int g = tid >> 2, j = tid & 3;
    int node = dst0 + g;
    int beg_ = beg[g];
    int cnt_ = cnt[g];
    float a0 = 0.f, a1 = 0.f, a2 = 0.f, a3 = 0.f;
    float a4 = 0.f, a5 = 0.f, a6 = 0.f, a7 = 0.f;
    int i = 0;
    for (; i + 8 <= cnt_; i += 8) {
        unsigned pk8[8]; uint4 v8[8];
#pragma unroll
        for (int t = 0; t < 8; ++t) pk8[t] = sorted[beg_ + i + t];        // LDS broadcast
#pragma unroll
        for (int t = 0; t < 8; ++t) v8[t] = hsv[(size_t)(pk8[t] >> BSH) * 4 + j];
#pragma unroll
        for (int t = 0; t < 8; ++t) {
            float2 f0 = __bfloat1622float2(*(__hip_bfloat162*)&v8[t].x);
            float2 f1 = __bfloat1622float2(*(__hip_bfloat162*)&v8[t].y);
            float2 f2 = __bfloat1622float2(*(__hip_bfloat162*)&v8[t].z);
            float2 f3 = __bfloat1622float2(*(__hip_bfloat162*)&v8[t].w);
            a0 += f0.x; a1 += f0.y; a2 += f1.x; a3 += f1.y;
            a4 += f2.x; a5 += f2.y; a6 += f3.x; a7 += f3.y;
        }
    }
#pragma unroll 4
    for (; i < cnt_; ++i) {
        unsigned pk = sorted[beg_ + i];
        uint4 v = hsv[(size_t)(pk >> BSH) * 4 + j];
        float2 f0 = __bfloat1622float2(*(__hip_bfloat162*)&v.x);
        float2 f1 = __bfloat1622float2(*(__hip_bfloat162*)&v.y);
        float2 f2 = __bfloat1622float2(*(__hip_bfloat162*)&v.z);
        float2 f3 = __bfloat1622float2(*(__hip_bfloat162*)&v.w);
        a0 += f0.x; a1 += f0.y; a2 += f1.x; a3 += f1.y;
        a4 += f2.x; a5 += f2.y; a6 += f3.x; a7 += f3.y;
    }
    if (node < n) {
        float dv = rsqrtf((float)cnt_ + 1.0f);
        uint4 sv = hsv[(size_t)node * 4 + j];                             // self (pre-scaled)
        float2 s0 = __bfloat1622float2(*(__hip_bfloat162*)&sv.x);
        float2 s1 = __bfloat1622float2(*(__hip_bfloat162*)&sv.y);
        float2 s2 = __bfloat1622float2(*(__hip_bfloat162*)&sv.z);
        float2 s3 = __bfloat1622float2(*(__hip_bfloat162*)&sv.w);
        float4 bv0 = *(const float4*)&bias[j * 8];
        float4 bv1 = *(const float4*)&bias[j * 8 + 4];
        float4 o0, o1;
        o0.x = (a0 + s0.x) * dv + bv0.x;
        o0.y = (a1 + s0.y) * dv + bv0.y;
        o0.z = (a2 + s1.x) * dv + bv0.z;
        o0.w = (a3 + s1.y) * dv + bv0.w;
        o1.x = (a4 + s2.x) * dv + bv1.x;
        o1.y = (a5 + s2.y) * dv + bv1.y;
        o1.z = (a6 + s3.x) * dv + bv1.z;
        o1.w = (a7 + s3.y) * dv + bv1.w;
        *(float4*)&out[(size_t)node * LATD + j * 8]     = o0;
        *(float4*)&out[(size_t)node * LATD + j * 8 + 4] = o1;
    }
}

// ---------------- fallback path (atomic scatter; uses UNSCALED h) ----------------
__global__ void count_k(const int* __restrict__ ei, const int* __restrict__ yei,
                        int* __restrict__ cnt, int e1, int e2) {
    int e = blockIdx.x * 256 + threadIdx.x;
    if (e >= e1 + e2) return;
    int src, dst; load_edge(ei, yei, e1, e2, e, src, dst);
    atomicAdd(&cnt[dst], 1);
}

__global__ void dinv_k(const int* __restrict__ cnt, float* __restrict__ dinv, int n) {
    int i = blockIdx.x * 256 + threadIdx.x;
    if (i < n) dinv[i] = rsqrtf((float)cnt[i] + 1.0f);
}

__global__ void selfbias_k(const float* __restrict__ dinv, const __hip_bfloat16* __restrict__ h,
                           const float* __restrict__ b, float* __restrict__ out, int total) {
    int idx = blockIdx.x * 256 + threadIdx.x;
    if (idx >= total) return;
    int i = idx >> 5, j = idx & 31;
    float d = dinv[i];
    out[idx] = __bfloat162float(h[idx]) * d * d + b[j];
}

__global__ void scatter_atomic_k(const int* __restrict__ ei, const int* __restrict__ yei,
                                 const float* __restrict__ dinv, const __hip_bfloat16* __restrict__ h,
                                 float* __restrict__ out, int e1, int e2) {
    int idx = blockIdx.x * 256 + threadIdx.x;
    int e = idx >> 5;
    if (e >= e1 + e2) return;
    int j = idx & 31;
    int src, dst; load_edge(ei, yei, e1, e2, e, src, dst);
    float norm = dinv[src] * dinv[dst];
    atomicAdd(&out[(size_t)dst * LATD + j], __bfloat162float(h[(size_t)src * LATD + j]) * norm);
}

static inline size_t aln(size_t x) { return (x + 255) & ~(size_t)255; }

extern "C" void kernel_launch(void* const* d_in, const int* in_sizes, int n_in,
                              void* d_out, int out_size, void* d_ws, size_t ws_size,
                              hipStream_t stream) {
    const float* x  = (const float*)d_in[0];
    const int* ei   = (const int*)d_in[1];
    const int* yei  = (const int*)d_in[2];
    const float* W  = (const float*)d_in[3];
    const float* b  = (const float*)d_in[4];
    float* out = (float*)d_out;

    int n  = in_sizes[0] / INCH;
    int e1 = in_sizes[1] / 2;
    int e2 = in_sizes[2] / 2;
    int E  = e1 + e2;
    int NB = (n + BW - 1) >> BSH;

    char* p = (char*)d_ws;
    size_t off = 0;
    float* dinv = (float*)(p + off);            off += aln((size_t)n * 4);
    __hip_bfloat16* h = (__hip_bfloat16*)(p + off); off += aln((size_t)n * LATD * 2);
    unsigned* bucketed = (unsigned*)(p + off);  size_t bucketed_off = off; off += aln((size_t)NB * CAP * 4);
    int* bcursor = (int*)(p + off);             off += aln((size_t)(1024 + n) * 4);
    int* deg = bcursor + 1024;
    __hip_bfloat16* Wf = (__hip_bfloat16*)(p + off); off += aln((size_t)INCH * LATD * 2);
    bool fast_ok = (off <= ws_size) && (NB <= 1024);

    if (fast_ok) {
        int ablocks = (E + ACH - 1) / ACH;
        prep_k<<<20, 256, 0, stream>>>(W, Wf, bcursor);
        passA_scatter_k<<<ablocks, 512, 0, stream>>>(ei, yei, e1, e2, bcursor, bucketed, NB);
        gemm_fused_k<<<NB, 512, 0, stream>>>(x, Wf, h, bucketed, bcursor, deg, n);  // hist+MFMA+scale
        passB2_k<<<NB, 512, 0, stream>>>(bucketed, bcursor, deg, h, b, out, n);
    } else {
        prep_k<<<20, 256, 0, stream>>>(W, Wf, bcursor);
        gemm_fused_k<<<(n + 127) / 128, 512, 0, stream>>>(x, Wf, h, nullptr, nullptr, nullptr, n); // unscaled
        int* cntf = (int*)(p + bucketed_off);
        zero_i32_k<<<(n + 255) / 256, 256, 0, stream>>>(cntf, n);
        count_k<<<(E + 255) / 256, 256, 0, stream>>>(ei, yei, cntf, e1, e2);
        dinv_k<<<(n + 255) / 256, 256, 0, stream>>>(cntf, dinv, n);
        selfbias_k<<<(out_size + 255) / 256, 256, 0, stream>>>(dinv, h, b, out, out_size);
        scatter_atomic_k<<<((size_t)E * LATD + 255) / 256, 256, 0, stream>>>(ei, yei, dinv, h, out, e1, e2);
    }
}